// Round 5
// baseline (259.607 us; speedup 1.0000x reference)
//
#include <hip/hip_runtime.h>

#define NUM_CLASSES 4096
#define ROWS 8192

// Fused: one block (256 threads = 4 waves) per row computes the per-row W1
// (identity: sum_c |cdf[c] - 1[c>=t]| = sum_j p[j]*|j-t|), then the
// last-finishing block reduces all 8192 row values in fixed order
// (deterministic) and writes the scalar.
__global__ __launch_bounds__(256) void w1_fused_kernel(const float* __restrict__ logits,
                                                       const int* __restrict__ targets,
                                                       float* __restrict__ out,
                                                       float* __restrict__ row_w1,
                                                       unsigned int* __restrict__ counter) {
    const int r = blockIdx.x;
    const int tid = threadIdx.x;
    const float4* rowp = reinterpret_cast<const float4*>(logits + (size_t)r * NUM_CLASSES);

    // Issue all four 16B loads up front (64 B/lane, fully coalesced).
    const float4 v0 = rowp[tid];
    const float4 v1 = rowp[256 + tid];
    const float4 v2 = rowp[512 + tid];
    const float4 v3 = rowp[768 + tid];
    const float t = (float)targets[r];

    // ---- Phase 1: block-wide max ----
    float m = fmaxf(fmaxf(fmaxf(v0.x, v0.y), fmaxf(v0.z, v0.w)),
                    fmaxf(fmaxf(v1.x, v1.y), fmaxf(v1.z, v1.w)));
    m = fmaxf(m, fmaxf(fmaxf(fmaxf(v2.x, v2.y), fmaxf(v2.z, v2.w)),
                       fmaxf(fmaxf(v3.x, v3.y), fmaxf(v3.z, v3.w))));
    #pragma unroll
    for (int off = 1; off < 64; off <<= 1) m = fmaxf(m, __shfl_xor(m, off, 64));

    __shared__ float smax[4];
    __shared__ float ssum[4];
    __shared__ float swsum[4];
    __shared__ int is_last_blk;
    const int wave = tid >> 6;
    if ((tid & 63) == 0) smax[wave] = m;
    __syncthreads();
    m = fmaxf(fmaxf(smax[0], smax[1]), fmaxf(smax[2], smax[3]));

    // ---- Phase 2: independent exps; split accumulators for ILP ----
    const float c = (float)(tid * 4) - t;
    float s0 = 0.f, s1 = 0.f, w0 = 0.f, w1 = 0.f;

#define W1_ACC(vv, base, S, W)                                              \
    {                                                                       \
        const float e0 = __expf(vv.x - m);                                  \
        const float e1 = __expf(vv.y - m);                                  \
        const float e2 = __expf(vv.z - m);                                  \
        const float e3 = __expf(vv.w - m);                                  \
        S += (e0 + e1) + (e2 + e3);                                         \
        W += e0 * fabsf(c + (base + 0.f)) + e1 * fabsf(c + (base + 1.f))   \
           + e2 * fabsf(c + (base + 2.f)) + e3 * fabsf(c + (base + 3.f)); \
    }

    W1_ACC(v0, 0.f, s0, w0)
    W1_ACC(v1, 1024.f, s1, w1)
    W1_ACC(v2, 2048.f, s0, w0)
    W1_ACC(v3, 3072.f, s1, w1)
#undef W1_ACC

    float s = s0 + s1;
    float w = w0 + w1;

    #pragma unroll
    for (int off = 1; off < 64; off <<= 1) {
        s += __shfl_xor(s, off, 64);
        w += __shfl_xor(w, off, 64);
    }
    if ((tid & 63) == 0) { ssum[wave] = s; swsum[wave] = w; }
    __syncthreads();

    if (tid == 0) {
        s = (ssum[0] + ssum[1]) + (ssum[2] + ssum[3]);
        w = (swsum[0] + swsum[1]) + (swsum[2] + swsum[3]);
        row_w1[r] = (w / s) * (1.0f / NUM_CLASSES);
        __threadfence();                       // device-scope release of row_w1[r]
        const unsigned int prev = atomicAdd(counter, 1u);
        is_last_blk = (prev == (unsigned int)(ROWS - 1)) ? 1 : 0;
    }
    __syncthreads();

    // ---- Last block: deterministic final reduction over all rows ----
    if (is_last_blk) {
        __threadfence();                       // device-scope acquire
        const float4* p = reinterpret_cast<const float4*>(row_w1);
        float acc = 0.0f;
        #pragma unroll
        for (int k = 0; k < 8; ++k) {          // 8192 floats = 2048 float4
            const float4 v = p[k * 256 + tid];
            acc += (v.x + v.y) + (v.z + v.w);
        }
        #pragma unroll
        for (int off = 1; off < 64; off <<= 1) acc += __shfl_xor(acc, off, 64);
        if ((tid & 63) == 0) ssum[wave] = acc; // reuse LDS
        __syncthreads();
        if (tid == 0) {
            out[0] = ((ssum[0] + ssum[1]) + (ssum[2] + ssum[3])) * (1.0f / ROWS);
        }
    }
}

extern "C" void kernel_launch(void* const* d_in, const int* in_sizes, int n_in,
                              void* d_out, int out_size, void* d_ws, size_t ws_size,
                              hipStream_t stream) {
    const float* logits = (const float*)d_in[0];
    const int* targets = (const int*)d_in[1];
    float* out = (float*)d_out;
    float* row_w1 = (float*)d_ws;                                   // 32 KB
    unsigned int* counter = (unsigned int*)((char*)d_ws + 32768);   // 4 B

    // Counter must be zero at every call (replays don't re-poison workspace).
    hipMemsetAsync(counter, 0, sizeof(unsigned int), stream);
    w1_fused_kernel<<<ROWS, 256, 0, stream>>>(logits, targets, out, row_w1, counter);
}

// Round 8
// 28.161 us; speedup vs baseline: 9.2186x; 9.2186x over previous
//
#include <hip/hip_runtime.h>

#define NUM_CLASSES 4096
#define ROWS 8192

// One WAVE (64 lanes) per row; 4 rows per 256-thread block; grid = ROWS/4.
// No __syncthreads, no LDS: all reductions are intra-wave shfl_xor.
// Each lane holds 16 float4 (64 floats) of its row in registers:
//   vec index = k*64 + lane  (k = 0..15)  -> wave covers 1 KiB contiguous per load.
//   element j = k*256 + lane*4 + e        -> distance d = |(lane*4 - t) + (k*256 + e)|
// W1-vs-delta identity: sum_c |cdf[c] - 1[c>=t]| = sum_j p[j]*|j - t|.
__global__ __launch_bounds__(256) void w1_row_kernel(const float* __restrict__ logits,
                                                     const int* __restrict__ targets,
                                                     float* __restrict__ row_w1) {
    const int tid = threadIdx.x;
    const int lane = tid & 63;
    const int wave = tid >> 6;
    const int r = blockIdx.x * 4 + wave;
    const float4* rowp = reinterpret_cast<const float4*>(logits + (size_t)r * NUM_CLASSES);

    // 16 coalesced float4 loads, all issued before first use (16 in flight).
    float4 v[16];
    #pragma unroll
    for (int k = 0; k < 16; ++k) v[k] = rowp[k * 64 + lane];
    const float t = (float)targets[r];

    // ---- Phase 1: row max (two parallel fmax chains, then shfl tree) ----
    float ma = fmaxf(fmaxf(v[0].x, v[0].y), fmaxf(v[0].z, v[0].w));
    float mb = fmaxf(fmaxf(v[1].x, v[1].y), fmaxf(v[1].z, v[1].w));
    #pragma unroll
    for (int k = 2; k < 16; k += 2) {
        ma = fmaxf(ma, fmaxf(fmaxf(v[k].x, v[k].y), fmaxf(v[k].z, v[k].w)));
        mb = fmaxf(mb, fmaxf(fmaxf(v[k + 1].x, v[k + 1].y), fmaxf(v[k + 1].z, v[k + 1].w)));
    }
    float m = fmaxf(ma, mb);
    #pragma unroll
    for (int off = 1; off < 64; off <<= 1) m = fmaxf(m, __shfl_xor(m, off, 64));

    // ---- Phase 2: 64 independent exps; split accumulators for ILP ----
    const float c = (float)(lane * 4) - t;
    float s0 = 0.f, s1 = 0.f, w0 = 0.f, w1 = 0.f;
    #pragma unroll
    for (int k = 0; k < 16; k += 2) {
        {
            const float base = (float)(k * 256);
            const float e0 = __expf(v[k].x - m);
            const float e1 = __expf(v[k].y - m);
            const float e2 = __expf(v[k].z - m);
            const float e3 = __expf(v[k].w - m);
            s0 += (e0 + e1) + (e2 + e3);
            w0 += e0 * fabsf(c + (base + 0.f)) + e1 * fabsf(c + (base + 1.f))
                + e2 * fabsf(c + (base + 2.f)) + e3 * fabsf(c + (base + 3.f));
        }
        {
            const float base = (float)((k + 1) * 256);
            const float e0 = __expf(v[k + 1].x - m);
            const float e1 = __expf(v[k + 1].y - m);
            const float e2 = __expf(v[k + 1].z - m);
            const float e3 = __expf(v[k + 1].w - m);
            s1 += (e0 + e1) + (e2 + e3);
            w1 += e0 * fabsf(c + (base + 0.f)) + e1 * fabsf(c + (base + 1.f))
                + e2 * fabsf(c + (base + 2.f)) + e3 * fabsf(c + (base + 3.f));
        }
    }
    float s = s0 + s1;
    float w = w0 + w1;

    // ---- wave sum reduction ----
    #pragma unroll
    for (int off = 1; off < 64; off <<= 1) {
        s += __shfl_xor(s, off, 64);
        w += __shfl_xor(w, off, 64);
    }
    if (lane == 0) row_w1[r] = (w / s) * (1.0f / NUM_CLASSES);
}

// Deterministic final reduction: one block sums all 8192 per-row values.
__global__ __launch_bounds__(256) void w1_reduce_kernel(const float* __restrict__ row_w1,
                                                        float* __restrict__ out) {
    const int tid = threadIdx.x;
    const float4* p = reinterpret_cast<const float4*>(row_w1);
    float acc = 0.0f;
    // 8192 floats = 2048 float4; 256 threads x 8 float4 each
    #pragma unroll
    for (int k = 0; k < 8; ++k) {
        const float4 v = p[k * 256 + tid];
        acc += (v.x + v.y) + (v.z + v.w);
    }

    #pragma unroll
    for (int off = 1; off < 64; off <<= 1) acc += __shfl_xor(acc, off, 64);

    __shared__ float sa[4];
    if ((tid & 63) == 0) sa[tid >> 6] = acc;
    __syncthreads();

    if (tid == 0) {
        out[0] = ((sa[0] + sa[1]) + (sa[2] + sa[3])) * (1.0f / ROWS);
    }
}

extern "C" void kernel_launch(void* const* d_in, const int* in_sizes, int n_in,
                              void* d_out, int out_size, void* d_ws, size_t ws_size,
                              hipStream_t stream) {
    const float* logits = (const float*)d_in[0];
    const int* targets = (const int*)d_in[1];
    float* out = (float*)d_out;
    float* row_w1 = (float*)d_ws;   // 8192 floats = 32 KB scratch

    w1_row_kernel<<<ROWS / 4, 256, 0, stream>>>(logits, targets, row_w1);
    w1_reduce_kernel<<<1, 256, 0, stream>>>(row_w1, out);
}

// Round 10
// 25.016 us; speedup vs baseline: 10.3778x; 1.1257x over previous
//
#include <hip/hip_runtime.h>

#define NUM_CLASSES 4096
#define ROWS 8192

typedef float floatx4 __attribute__((ext_vector_type(4)));

// One block (256 threads = 4 waves) per row — measured-best structure (R4: 27.46us).
// Logits are read-once/streaming: nontemporal loads (clang ext_vector type —
// HIP_vector_type float4 is a struct and the builtin rejects it) bypass cache
// allocation. Phase 1: block max (register tree + shfl + LDS). Phase 2:
// independent exps. Identity: sum_c |cdf[c] - 1[c>=t]| = sum_j p[j]*|j - t|.
__global__ __launch_bounds__(256) void w1_row_kernel(const float* __restrict__ logits,
                                                     const int* __restrict__ targets,
                                                     float* __restrict__ row_w1) {
    const int r = blockIdx.x;
    const int tid = threadIdx.x;
    const floatx4* rowp = reinterpret_cast<const floatx4*>(logits + (size_t)r * NUM_CLASSES);

    // Four 16B nontemporal loads issued up front (64 B/lane, fully coalesced).
    const floatx4 v0 = __builtin_nontemporal_load(rowp + tid);
    const floatx4 v1 = __builtin_nontemporal_load(rowp + 256 + tid);
    const floatx4 v2 = __builtin_nontemporal_load(rowp + 512 + tid);
    const floatx4 v3 = __builtin_nontemporal_load(rowp + 768 + tid);
    const float t = (float)targets[r];

    // ---- Phase 1: block-wide max ----
    float m = fmaxf(fmaxf(fmaxf(v0.x, v0.y), fmaxf(v0.z, v0.w)),
                    fmaxf(fmaxf(v1.x, v1.y), fmaxf(v1.z, v1.w)));
    m = fmaxf(m, fmaxf(fmaxf(fmaxf(v2.x, v2.y), fmaxf(v2.z, v2.w)),
                       fmaxf(fmaxf(v3.x, v3.y), fmaxf(v3.z, v3.w))));
    #pragma unroll
    for (int off = 1; off < 64; off <<= 1) m = fmaxf(m, __shfl_xor(m, off, 64));

    __shared__ float smax[4];
    __shared__ float ssum[4];
    __shared__ float swsum[4];
    const int wave = tid >> 6;
    if ((tid & 63) == 0) smax[wave] = m;
    __syncthreads();
    m = fmaxf(fmaxf(smax[0], smax[1]), fmaxf(smax[2], smax[3]));

    // ---- Phase 2: independent exps; split accumulators for ILP ----
    // element j = chunk*1024 + tid*4 + e  ->  d = |(tid*4 - t) + (chunk*1024 + e)|
    const float c = (float)(tid * 4) - t;
    float s0 = 0.f, s1 = 0.f, w0 = 0.f, w1 = 0.f;

#define W1_ACC(vv, base, S, W)                                              \
    {                                                                       \
        const float e0 = __expf(vv.x - m);                                  \
        const float e1 = __expf(vv.y - m);                                  \
        const float e2 = __expf(vv.z - m);                                  \
        const float e3 = __expf(vv.w - m);                                  \
        S += (e0 + e1) + (e2 + e3);                                         \
        W += e0 * fabsf(c + (base + 0.f)) + e1 * fabsf(c + (base + 1.f))   \
           + e2 * fabsf(c + (base + 2.f)) + e3 * fabsf(c + (base + 3.f)); \
    }

    W1_ACC(v0, 0.f, s0, w0)
    W1_ACC(v1, 1024.f, s1, w1)
    W1_ACC(v2, 2048.f, s0, w0)
    W1_ACC(v3, 3072.f, s1, w1)
#undef W1_ACC

    float s = s0 + s1;
    float w = w0 + w1;

    // ---- plain-add block reduction (shared m, no rescale) ----
    #pragma unroll
    for (int off = 1; off < 64; off <<= 1) {
        s += __shfl_xor(s, off, 64);
        w += __shfl_xor(w, off, 64);
    }
    if ((tid & 63) == 0) { ssum[wave] = s; swsum[wave] = w; }
    __syncthreads();

    if (tid == 0) {
        s = (ssum[0] + ssum[1]) + (ssum[2] + ssum[3]);
        w = (swsum[0] + swsum[1]) + (swsum[2] + swsum[3]);
        row_w1[r] = (w / s) * (1.0f / NUM_CLASSES);
    }
}

// Deterministic final reduction: one block sums all 8192 per-row values.
__global__ __launch_bounds__(256) void w1_reduce_kernel(const float* __restrict__ row_w1,
                                                        float* __restrict__ out) {
    const int tid = threadIdx.x;
    const float4* p = reinterpret_cast<const float4*>(row_w1);
    float acc = 0.0f;
    // 8192 floats = 2048 float4; 256 threads x 8 float4 each
    #pragma unroll
    for (int k = 0; k < 8; ++k) {
        const float4 v = p[k * 256 + tid];
        acc += (v.x + v.y) + (v.z + v.w);
    }

    #pragma unroll
    for (int off = 1; off < 64; off <<= 1) acc += __shfl_xor(acc, off, 64);

    __shared__ float sa[4];
    if ((tid & 63) == 0) sa[tid >> 6] = acc;
    __syncthreads();

    if (tid == 0) {
        out[0] = ((sa[0] + sa[1]) + (sa[2] + sa[3])) * (1.0f / ROWS);
    }
}

extern "C" void kernel_launch(void* const* d_in, const int* in_sizes, int n_in,
                              void* d_out, int out_size, void* d_ws, size_t ws_size,
                              hipStream_t stream) {
    const float* logits = (const float*)d_in[0];
    const int* targets = (const int*)d_in[1];
    float* out = (float*)d_out;
    float* row_w1 = (float*)d_ws;   // 8192 floats = 32 KB scratch

    w1_row_kernel<<<ROWS, 256, 0, stream>>>(logits, targets, row_w1);
    w1_reduce_kernel<<<1, 256, 0, stream>>>(row_w1, out);
}